// Round 5
// baseline (93.695 us; speedup 1.0000x reference)
//
#include <hip/hip_runtime.h>
#include <hip/hip_bf16.h>

#define T_DIM 128
#define S_DIM 128
#define B_DIM 32
#define H_DIM 512
#define C_DIM 512
#define M_DIM 256
#define NEG_BIG -1e8f
#define K2LOG2E 2.8853900817779268f   // 2*log2(e): exp(2x) = exp2(K*x)

typedef __attribute__((ext_vector_type(8))) short shortx8;   // 8 bf16
typedef __attribute__((ext_vector_type(4))) float floatx4;

// f32 -> bf16 RNE, packed pair
__device__ __forceinline__ unsigned bfpair(float a, float b) {
  unsigned ua = __builtin_bit_cast(unsigned, a); ua += 0x7fffu + ((ua >> 16) & 1u);
  unsigned ub = __builtin_bit_cast(unsigned, b); ub += 0x7fffu + ((ub >> 16) & 1u);
  return (ua >> 16) | (ub & 0xffff0000u);
}
__device__ __forceinline__ uint4 pack2(const float4& a, const float4& b) {
  uint4 o;
  o.x = bfpair(a.x, a.y); o.y = bfpair(a.z, a.w);
  o.z = bfpair(b.x, b.y); o.w = bfpair(b.z, b.w);
  return o;
}
__device__ __forceinline__ ushort bf1(float a) {
  unsigned ua = __builtin_bit_cast(unsigned, a); ua += 0x7fffu + ((ua >> 16) & 1u);
  return (ushort)(ua >> 16);
}

// ---------------------------------------------------------------------------
// Pre-convert 5 f32 regions to bf16 (8 elements per thread).
// ---------------------------------------------------------------------------
__device__ __forceinline__ void cvt8(const float* __restrict__ s,
                                     ushort* __restrict__ d, int g) {
  const float4 x = *(const float4*)(s + (size_t)g * 8);
  const float4 y = *(const float4*)(s + (size_t)g * 8 + 4);
  uint4 o;
  o.x = bfpair(x.x, x.y); o.y = bfpair(x.z, x.w);
  o.z = bfpair(y.x, y.y); o.w = bfpair(y.z, y.w);
  *(uint4*)(d + (size_t)g * 8) = o;
}

__global__ __launch_bounds__(256) void cvt_kernel(
    const float* a0, ushort* b0, int c0, const float* a1, ushort* b1, int c1,
    const float* a2, ushort* b2, int c2, const float* a3, ushort* b3, int c3,
    const float* a4, ushort* b4, int c4) {
  int g = blockIdx.x * 256 + threadIdx.x;
  if (g < c0) { cvt8(a0, b0, g); return; } g -= c0;
  if (g < c1) { cvt8(a1, b1, g); return; } g -= c1;
  if (g < c2) { cvt8(a2, b2, g); return; } g -= c2;
  if (g < c3) { cvt8(a3, b3, g); return; } g -= c3;
  if (g < c4) { cvt8(a4, b4, g); }
}

// ---------------------------------------------------------------------------
// Shared MFMA core, bf16 operands. Y(n,m) = sum_k X[n][k]*W[m][k].
// 64x64 tile, BK=64, 4 waves (2x2), 2x2 frags of 16x16x32, XOR-swizzled LDS,
// register-prefetch pipeline (next tile's loads issued right after barrier).
// xptr/wptr pre-offset by row*stride + (ls<<4); advance 64 elems per iter.
// ---------------------------------------------------------------------------
__device__ __forceinline__ void gemm_core_bf16(
    const ushort* __restrict__ xptr, const ushort* __restrict__ wptr, int nk,
    ushort* Xs, ushort* Ws, int tid, floatx4 acc[2][2]) {
  const int lane = tid & 63, wave = tid >> 6;
  const int wn = wave & 1, wm = wave >> 1;
  const int l15 = lane & 15, lhi = lane >> 4;
  const int lr = tid & 63, ls = tid >> 6;
  const int slot0 = (((2 * ls) ^ (lr & 7)) << 4);
  const int slot1 = (((2 * ls + 1) ^ (lr & 7)) << 4);
  char* xrow = (char*)Xs + lr * 128;
  char* wrow = (char*)Ws + lr * 128;

  uint4 xu[2], wu[2];
#define LOADXW                                                       \
  xu[0] = ((const uint4*)xptr)[0]; xu[1] = ((const uint4*)xptr)[1];  \
  wu[0] = ((const uint4*)wptr)[0]; wu[1] = ((const uint4*)wptr)[1];
  LOADXW
  for (int it = 0; it < nk; ++it) {
    __syncthreads();   // previous tile's readers done
    *(uint4*)(xrow + slot0) = xu[0];
    *(uint4*)(xrow + slot1) = xu[1];
    *(uint4*)(wrow + slot0) = wu[0];
    *(uint4*)(wrow + slot1) = wu[1];
    __syncthreads();
    if (it + 1 < nk) {   // issue next tile's loads; latency hides under MFMA
      xptr += 64; wptr += 64;
      LOADXW
    }
#pragma unroll
    for (int ks = 0; ks < 2; ++ks) {
      const int slot = lhi + (ks << 2);
      shortx8 af[2], bfr[2];
#pragma unroll
      for (int fi = 0; fi < 2; ++fi) {
        const int row = wn * 32 + fi * 16 + l15;
        af[fi] = *(const shortx8*)((const char*)Xs + row * 128 + ((slot ^ (row & 7)) << 4));
      }
#pragma unroll
      for (int fj = 0; fj < 2; ++fj) {
        const int col = wm * 32 + fj * 16 + l15;
        bfr[fj] = *(const shortx8*)((const char*)Ws + col * 128 + ((slot ^ (col & 7)) << 4));
      }
#pragma unroll
      for (int fi = 0; fi < 2; ++fi)
#pragma unroll
        for (int fj = 0; fj < 2; ++fj)
          acc[fi][fj] = __builtin_amdgcn_mfma_f32_16x16x32_bf16(af[fi], bfr[fj], acc[fi][fj], 0, 0, 0);
    }
  }
#undef LOADXW
}

// ---------------------------------------------------------------------------
// One launch, three GEMM sets (all K=512, bf16 in):
//   bid [0,256):    EH (T*B,M) f32 = exp(2 * hid . Wh^T)      64n x 4m tiles
//   bid [256,512):  EC (S*B,M) f32 = exp(2 * ctx . Wc^T)      64n x 4m tiles
//   bid [512,1024): CWT ((S,B),H) bf16 = ctx . Wa^T           64n x 8m tiles
// All X-sides read coalesced contiguous rows; weights are L2-resident.
// ---------------------------------------------------------------------------
__global__ __launch_bounds__(256) void gemm_multi(
    const ushort* __restrict__ HB, const ushort* __restrict__ WhB, float* __restrict__ EH,
    const ushort* __restrict__ CB, const ushort* __restrict__ WcB, float* __restrict__ EC,
    const ushort* __restrict__ WaB, ushort* __restrict__ CWT) {
  __shared__ ushort Xs[4096];
  __shared__ ushort Ws[4096];
  const int tid = threadIdx.x;
  const int bid = blockIdx.x;
  const int lr = tid & 63, ls = tid >> 6;

  const ushort *X, *W;
  int n0, m0;
  if (bid < 512) {
    const int lb = bid & 255;
    n0 = (lb >> 2) << 6; m0 = (lb & 3) << 6;
    X = (bid < 256) ? HB : CB;
    W = (bid < 256) ? WhB : WcB;
  } else {
    const int lb = bid - 512;
    n0 = (lb >> 3) << 6;          // (s,b) row tile
    m0 = (lb & 7) << 6;           // h tile
    X = CB;
    W = WaB;
  }

  floatx4 acc[2][2];
#pragma unroll
  for (int i = 0; i < 2; ++i)
#pragma unroll
    for (int j = 0; j < 2; ++j) acc[i][j] = (floatx4){0.f, 0.f, 0.f, 0.f};

  const ushort* xptr = X + (size_t)(n0 + lr) * 512 + (ls << 4);
  const ushort* wptr = W + (size_t)(m0 + lr) * 512 + (ls << 4);
  gemm_core_bf16(xptr, wptr, 8, Xs, Ws, tid, acc);

  const int lane = tid & 63, wave = tid >> 6;
  const int wn = wave & 1, wm = wave >> 1;
  const int l15 = lane & 15, lhi = lane >> 4;
  if (bid < 512) {
    float* Y = (bid < 256) ? EH : EC;
#pragma unroll
    for (int fi = 0; fi < 2; ++fi)
#pragma unroll
      for (int fj = 0; fj < 2; ++fj)
#pragma unroll
        for (int r = 0; r < 4; ++r) {
          const int row = n0 + wn * 32 + fi * 16 + lhi * 4 + r;
          const int col = m0 + wm * 32 + fj * 16 + l15;
          Y[(size_t)row * M_DIM + col] = __builtin_amdgcn_exp2f(K2LOG2E * acc[fi][fj][r]);
        }
  } else {
#pragma unroll
    for (int fi = 0; fi < 2; ++fi)
#pragma unroll
      for (int fj = 0; fj < 2; ++fj)
#pragma unroll
        for (int r = 0; r < 4; ++r) {
          const int row = n0 + wn * 32 + fi * 16 + lhi * 4 + r;
          const int col = m0 + wm * 32 + fj * 16 + l15;
          CWT[(size_t)row * H_DIM + col] = bf1(acc[fi][fj][r]);
        }
  }
}

// ---------------------------------------------------------------------------
// z (T,B,H) = alpha_b (T,S) . CW_b (S,H), batched over b. K = S = 128.
// X = AWS f32 (T,B,S) rows (t,b); W = CWT bf16 ((s,b),H), transposed into LDS
// during staging (72-elem padded rows -> 2-way conflicts, free).
// ---------------------------------------------------------------------------
__global__ __launch_bounds__(256) void zgemm_kernel(
    const float* __restrict__ AWS, const ushort* __restrict__ CWT,
    float* __restrict__ z) {
  __shared__ ushort Xs[4096];
  __shared__ ushort WsT[64 * 72];   // [h][s], row stride 72 (144B, 16B-aligned)
  const int tid = threadIdx.x;
  const int m0 = blockIdx.x << 6;          // h
  const int n0 = blockIdx.y << 6;          // t
  const int b = blockIdx.z;
  const int lane = tid & 63, wave = tid >> 6;
  const int wn = wave & 1, wm = wave >> 1;
  const int l15 = lane & 15, lhi = lane >> 4;
  const int lr = tid & 63, ls = tid >> 6;
  const int slot0 = (((2 * ls) ^ (lr & 7)) << 4);
  const int slot1 = (((2 * ls + 1) ^ (lr & 7)) << 4);
  char* xrow = (char*)Xs + lr * 128;

  // Preload both K-halves (K=128 -> 2 iters of 64).
  float4 xf[2][4];
  uint4 wv[2][2];
#pragma unroll
  for (int it = 0; it < 2; ++it) {
    const float* p = AWS + ((size_t)(n0 + lr) * B_DIM + b) * S_DIM + it * 64 + (ls << 4);
    xf[it][0] = ((const float4*)p)[0]; xf[it][1] = ((const float4*)p)[1];
    xf[it][2] = ((const float4*)p)[2]; xf[it][3] = ((const float4*)p)[3];
    const ushort* q = CWT + ((size_t)(it * 64 + lr) * B_DIM + b) * H_DIM + m0 + ls * 8;
    wv[it][0] = *(const uint4*)q;
    wv[it][1] = *(const uint4*)(q + 32);
  }

  floatx4 acc[2][2];
#pragma unroll
  for (int i = 0; i < 2; ++i)
#pragma unroll
    for (int j = 0; j < 2; ++j) acc[i][j] = (floatx4){0.f, 0.f, 0.f, 0.f};

#pragma unroll
  for (int it = 0; it < 2; ++it) {
    __syncthreads();
    *(uint4*)(xrow + slot0) = pack2(xf[it][0], xf[it][1]);
    *(uint4*)(xrow + slot1) = pack2(xf[it][2], xf[it][3]);
#pragma unroll
    for (int q = 0; q < 2; ++q) {
      const int hb = ls * 8 + q * 32;          // h offset within tile
      const ushort* vs = (const ushort*)&wv[it][q];
#pragma unroll
      for (int i = 0; i < 8; ++i) WsT[(hb + i) * 72 + lr] = vs[i];
    }
    __syncthreads();
#pragma unroll
    for (int ks = 0; ks < 2; ++ks) {
      const int slot = lhi + (ks << 2);
      shortx8 af[2], bfr[2];
#pragma unroll
      for (int fi = 0; fi < 2; ++fi) {
        const int row = wn * 32 + fi * 16 + l15;
        af[fi] = *(const shortx8*)((const char*)Xs + row * 128 + ((slot ^ (row & 7)) << 4));
      }
#pragma unroll
      for (int fj = 0; fj < 2; ++fj) {
        const int col = wm * 32 + fj * 16 + l15;
        bfr[fj] = *(const shortx8*)((const char*)WsT + col * 144 + (slot << 4));
      }
#pragma unroll
      for (int fi = 0; fi < 2; ++fi)
#pragma unroll
        for (int fj = 0; fj < 2; ++fj)
          acc[fi][fj] = __builtin_amdgcn_mfma_f32_16x16x32_bf16(af[fi], bfr[fj], acc[fi][fj], 0, 0, 0);
    }
  }

#pragma unroll
  for (int fi = 0; fi < 2; ++fi)
#pragma unroll
    for (int fj = 0; fj < 2; ++fj)
#pragma unroll
      for (int r = 0; r < 4; ++r) {
        const int t = n0 + wn * 32 + fi * 16 + lhi * 4 + r;
        const int h = m0 + wm * 32 + fj * 16 + l15;
        z[((size_t)t * B_DIM + b) * H_DIM + h] = acc[fi][fj][r];
      }
}

// ---------------------------------------------------------------------------
// Fused scores + softmax, exp-factored:
//   alpha(s) = softmax_s( -2 * sum_m w[m] * rcp(EH[t,b,m]*EC[s,b,m] + 1) )
// Writes AWS in (T,B,S) layout (coalesced; feeds zgemm X-side directly).
// ---------------------------------------------------------------------------
__global__ __launch_bounds__(256) void scores_kernel(
    const float* __restrict__ EH, const float* __restrict__ EC,
    const float* __restrict__ w_ff, const float* __restrict__ ctx_mask,
    float* __restrict__ aws) {
  __shared__ float4 ec[2][8][128];
  __shared__ float4 eh[2][8][8];
  __shared__ float4 wf[2][8];
  __shared__ float msk[S_DIM];
  const int tid = threadIdx.x;
  const int b = blockIdx.y;
  const int t0 = blockIdx.x << 3;
  const int tt = tid >> 6;
  const int st = tid & 63;

  if (tid < S_DIM) msk[tid] = ctx_mask[(size_t)tid * B_DIM + b];

  float4 rec[4], reh, rwf;
#define SLOAD(C)                                                                \
  {                                                                             \
    _Pragma("unroll")                                                           \
    for (int i = 0; i < 4; ++i) {                                               \
      const int idx = tid + (i << 8);                                           \
      const int s_ = idx >> 3, q_ = idx & 7;                                    \
      rec[i] = *(const float4*)(EC + ((size_t)s_ * B_DIM + b) * M_DIM + ((C) << 5) + (q_ << 2)); \
    }                                                                           \
    if (tid < 64)                                                               \
      reh = *(const float4*)(EH + ((size_t)(t0 + (tid >> 3)) * B_DIM + b) * M_DIM + ((C) << 5) + ((tid & 7) << 2)); \
    if (tid < 8) rwf = *(const float4*)(w_ff + ((C) << 5) + (tid << 2));        \
  }
#define SSTORE(BUF)                                                             \
  {                                                                             \
    _Pragma("unroll")                                                           \
    for (int i = 0; i < 4; ++i) {                                               \
      const int idx = tid + (i << 8);                                           \
      ec[BUF][idx & 7][idx >> 3] = rec[i];                                      \
    }                                                                           \
    if (tid < 64) eh[BUF][tid & 7][tid >> 3] = reh;                             \
    if (tid < 8) wf[BUF][tid] = rwf;                                            \
  }

  floatx4 acc[2][2];
#pragma unroll
  for (int i = 0; i < 2; ++i)
#pragma unroll
    for (int j = 0; j < 2; ++j) acc[i][j] = (floatx4){0.f, 0.f, 0.f, 0.f};

  SLOAD(0)
  SSTORE(0)
  __syncthreads();

  for (int c = 0; c < 8; ++c) {
    const int cur = c & 1;
    if (c < 7) SLOAD(c + 1)
#pragma unroll
    for (int q = 0; q < 8; ++q) {
      const float4 w4 = wf[cur][q];
      const float4 e0 = eh[cur][q][2 * tt], e1 = eh[cur][q][2 * tt + 1];
      const float4 c0 = ec[cur][q][st],     c1 = ec[cur][q][st + 64];
#define ACC1(A, E, Cc)                                                 \
  A[0] += w4.x * __builtin_amdgcn_rcpf(E.x * Cc.x + 1.f);              \
  A[1] += w4.y * __builtin_amdgcn_rcpf(E.y * Cc.y + 1.f);              \
  A[2] += w4.z * __builtin_amdgcn_rcpf(E.z * Cc.z + 1.f);              \
  A[3] += w4.w * __builtin_amdgcn_rcpf(E.w * Cc.w + 1.f);
      ACC1(acc[0][0], e0, c0) ACC1(acc[0][1], e0, c1)
      ACC1(acc[1][0], e1, c0) ACC1(acc[1][1], e1, c1)
#undef ACC1
    }
    if (c < 7) {
      SSTORE(cur ^ 1)
      __syncthreads();
    }
  }
#undef SLOAD
#undef SSTORE

  const float mk0 = msk[st], mk1 = msk[st + 64];
  float sc[2][2];
#pragma unroll
  for (int ti = 0; ti < 2; ++ti) {
    const floatx4 a0 = acc[ti][0], a1 = acc[ti][1];
    sc[ti][0] = (mk0 > 0.f) ? -2.f * (a0[0] + a0[1] + a0[2] + a0[3]) : NEG_BIG;
    sc[ti][1] = (mk1 > 0.f) ? -2.f * (a1[0] + a1[1] + a1[2] + a1[3]) : NEG_BIG;
  }
#pragma unroll
  for (int ti = 0; ti < 2; ++ti) {
    float mx = fmaxf(sc[ti][0], sc[ti][1]);
#pragma unroll
    for (int off = 32; off > 0; off >>= 1) mx = fmaxf(mx, __shfl_xor(mx, off));
    const float e0 = __expf(sc[ti][0] - mx), e1 = __expf(sc[ti][1] - mx);
    float sum = e0 + e1;
#pragma unroll
    for (int off = 32; off > 0; off >>= 1) sum += __shfl_xor(sum, off);
    const float rinv = 1.f / sum;
    float* w = aws + ((size_t)(t0 + 2 * tt + ti) * B_DIM + b) * S_DIM;
    w[st] = e0 * rinv;
    w[st + 64] = e1 * rinv;
  }
}

// ---------------------------------------------------------------------------
// AWS (T,B,S) -> out (T,S,B). One block per t.
// ---------------------------------------------------------------------------
__global__ __launch_bounds__(256) void alpha_tr_kernel(
    const float* __restrict__ aws, float* __restrict__ aout) {
  __shared__ float al[32][129];
  const int t = blockIdx.x;
  const int tid = threadIdx.x;
  {
    const int b_ = tid >> 3, q = tid & 7;
    const float* src = aws + ((size_t)t * B_DIM + b_) * S_DIM + q * 16;
#pragma unroll
    for (int i = 0; i < 4; ++i)
      *(float4*)&al[b_][q * 16 + i * 4] = ((const float4*)src)[i];
  }
  __syncthreads();
  {
    const int s = tid >> 1, half = tid & 1;
    float* dst = aout + ((size_t)t * S_DIM + s) * B_DIM + half * 16;
#pragma unroll
    for (int i = 0; i < 4; ++i) {
      float4 o;
      o.x = al[half * 16 + i * 4 + 0][s];
      o.y = al[half * 16 + i * 4 + 1][s];
      o.z = al[half * 16 + i * 4 + 2][s];
      o.w = al[half * 16 + i * 4 + 3][s];
      ((float4*)dst)[i] = o;
    }
  }
}

// ---------------------------------------------------------------------------
extern "C" void kernel_launch(void* const* d_in, const int* in_sizes, int n_in,
                              void* d_out, int out_size, void* d_ws, size_t ws_size,
                              hipStream_t stream) {
  const float* hid       = (const float*)d_in[0];   // (T,B,H)
  const float* ctx       = (const float*)d_in[1];   // (S,B,C)
  const float* ctx_mask  = (const float*)d_in[2];   // (S,B)
  const float* W_hid2mid = (const float*)d_in[3];   // (M,H)
  const float* W_ctx2mid = (const float*)d_in[4];   // (M,C)
  const float* w_ff      = (const float*)d_in[5];   // (M,)
  const float* W_att2hid = (const float*)d_in[6];   // (H,C)
  float* out = (float*)d_out;
  float* ws  = (float*)d_ws;

  const size_t MEG = 1 << 20;
  float*  EH  = ws;                            // 1M f32
  float*  EC  = ws + MEG;                      // 1M f32
  float*  AWS = ws + 2 * MEG;                  // (T,B,S) 0.5M f32
  ushort* CWT = (ushort*)(ws + 2 * MEG + MEG / 2);  // ((S,B),H) 2M bf16
  ushort* HB  = (ushort*)(ws + 4 * MEG);       // hid bf16, 2M
  ushort* CB  = (ushort*)(ws + 5 * MEG);       // ctx bf16, 2M
  ushort* WhB = (ushort*)(ws + 6 * MEG);       // 128K
  ushort* WcB = WhB + 131072;                  // 128K
  ushort* WaB = WcB + 131072;                  // 256K
  float* alpha_out = out;                               // (T,S,B)
  float* z_out     = out + T_DIM * S_DIM * B_DIM;       // (T,B,H)

  dim3 blk(256);
  cvt_kernel<<<2304, blk, 0, stream>>>(hid, HB, 262144, ctx, CB, 262144,
                                       W_hid2mid, WhB, 16384, W_ctx2mid, WcB, 16384,
                                       W_att2hid, WaB, 32768);
  // EH = exp(2*hid.Wh^T), EC = exp(2*ctx.Wc^T), CWT = ctx.Wa^T (bf16)
  gemm_multi<<<1024, blk, 0, stream>>>(HB, WhB, EH, CB, WcB, EC, WaB, CWT);
  // fused tanh-scores + masked softmax -> AWS (T,B,S)
  scores_kernel<<<dim3(T_DIM / 8, B_DIM), blk, 0, stream>>>(EH, EC, w_ff, ctx_mask, AWS);
  // alpha output (T,S,B)
  alpha_tr_kernel<<<T_DIM, blk, 0, stream>>>(AWS, alpha_out);
  // z (T,B,H) = alpha_b . CW_b
  zgemm_kernel<<<dim3(H_DIM / 64, T_DIM / 64, B_DIM), blk, 0, stream>>>(AWS, CWT, z_out);
}

// Round 6
// 60.528 us; speedup vs baseline: 1.5480x; 1.5480x over previous
//
#include <hip/hip_runtime.h>
#include <hip/hip_bf16.h>

#define T_DIM 128
#define S_DIM 128
#define B_DIM 32
#define H_DIM 512
#define C_DIM 512
#define M_DIM 256
#define NEG_BIG -1e8f
#define K2LOG2E 2.8853900817779268f   // 2*log2(e): exp(2x) = exp2(K*x)

typedef __attribute__((ext_vector_type(8))) short shortx8;   // 8 bf16
typedef __attribute__((ext_vector_type(4))) float floatx4;

// f32 -> bf16 RNE, packed pair
__device__ __forceinline__ unsigned bfpair(float a, float b) {
  unsigned ua = __builtin_bit_cast(unsigned, a); ua += 0x7fffu + ((ua >> 16) & 1u);
  unsigned ub = __builtin_bit_cast(unsigned, b); ub += 0x7fffu + ((ub >> 16) & 1u);
  return (ua >> 16) | (ub & 0xffff0000u);
}
__device__ __forceinline__ uint4 pack2(const float4& a, const float4& b) {
  uint4 o;
  o.x = bfpair(a.x, a.y); o.y = bfpair(a.z, a.w);
  o.z = bfpair(b.x, b.y); o.w = bfpair(b.z, b.w);
  return o;
}
__device__ __forceinline__ ushort bf1(float a) {
  unsigned ua = __builtin_bit_cast(unsigned, a); ua += 0x7fffu + ((ua >> 16) & 1u);
  return (ushort)(ua >> 16);
}

// ---------------------------------------------------------------------------
// Pre-convert 5 f32 regions to bf16 (8 elements per thread).
// ---------------------------------------------------------------------------
__device__ __forceinline__ void cvt8(const float* __restrict__ s,
                                     ushort* __restrict__ d, int g) {
  const float4 x = *(const float4*)(s + (size_t)g * 8);
  const float4 y = *(const float4*)(s + (size_t)g * 8 + 4);
  uint4 o;
  o.x = bfpair(x.x, x.y); o.y = bfpair(x.z, x.w);
  o.z = bfpair(y.x, y.y); o.w = bfpair(y.z, y.w);
  *(uint4*)(d + (size_t)g * 8) = o;
}

__global__ __launch_bounds__(256) void cvt_kernel(
    const float* a0, ushort* b0, int c0, const float* a1, ushort* b1, int c1,
    const float* a2, ushort* b2, int c2, const float* a3, ushort* b3, int c3,
    const float* a4, ushort* b4, int c4) {
  int g = blockIdx.x * 256 + threadIdx.x;
  if (g < c0) { cvt8(a0, b0, g); return; } g -= c0;
  if (g < c1) { cvt8(a1, b1, g); return; } g -= c1;
  if (g < c2) { cvt8(a2, b2, g); return; } g -= c2;
  if (g < c3) { cvt8(a3, b3, g); return; } g -= c3;
  if (g < c4) { cvt8(a4, b4, g); }
}

// ---------------------------------------------------------------------------
// Shared MFMA core, bf16 operands. Y(n,m) = sum_k X[n][k]*W[m][k].
// 64x64 tile, BK=64, 4 waves (2x2), 2x2 frags of 16x16x32, XOR-swizzled LDS,
// register-prefetch pipeline.
// COALESCED staging: thread (r=tid>>3, c8=tid&7) loads rows r and r+32,
// 16B at k-octet c8 -> lanes 0..7 cover 128B contiguous per row; a wave
// issues 8 full-line requests per load (was 64 scattered lines with the old
// lane-per-row mapping -- the round-5 latency disaster).
// LDS: slot (c8 ^ (r&7)) -> 64-slot permutation per wave, conflict-free b128.
// ---------------------------------------------------------------------------
__device__ __forceinline__ void gemm_core_bf16(
    const ushort* __restrict__ X, const ushort* __restrict__ W,
    int n0, int m0, int K, int nk, ushort* Xs, ushort* Ws, int tid,
    floatx4 acc[2][2]) {
  const int lane = tid & 63;
  const int wave = tid >> 6, wn = wave & 1, wm = wave >> 1;
  const int l15 = lane & 15, lhi = lane >> 4;
  const int r = tid >> 3, c8 = tid & 7;
  const int sw0 = (c8 ^ (r & 7)) << 4;            // (r+32)&7 == r&7
  char* xr0 = (char*)Xs + r * 128 + sw0;
  char* xr1 = (char*)Xs + (r + 32) * 128 + sw0;
  char* wr0 = (char*)Ws + r * 128 + sw0;
  char* wr1 = (char*)Ws + (r + 32) * 128 + sw0;

  const ushort* xp0 = X + (size_t)(n0 + r) * K + c8 * 8;
  const ushort* xp1 = xp0 + (size_t)32 * K;
  const ushort* wp0 = W + (size_t)(m0 + r) * K + c8 * 8;
  const ushort* wp1 = wp0 + (size_t)32 * K;

  uint4 xu0 = *(const uint4*)xp0, xu1 = *(const uint4*)xp1;
  uint4 wu0 = *(const uint4*)wp0, wu1 = *(const uint4*)wp1;

  for (int it = 0; it < nk; ++it) {
    __syncthreads();   // previous tile's readers done
    *(uint4*)xr0 = xu0; *(uint4*)xr1 = xu1;
    *(uint4*)wr0 = wu0; *(uint4*)wr1 = wu1;
    __syncthreads();
    if (it + 1 < nk) {   // issue next tile's loads; latency hides under MFMA
      xp0 += 64; xp1 += 64; wp0 += 64; wp1 += 64;
      xu0 = *(const uint4*)xp0; xu1 = *(const uint4*)xp1;
      wu0 = *(const uint4*)wp0; wu1 = *(const uint4*)wp1;
    }
#pragma unroll
    for (int ks = 0; ks < 2; ++ks) {
      const int slot = lhi + (ks << 2);
      shortx8 af[2], bfr[2];
#pragma unroll
      for (int fi = 0; fi < 2; ++fi) {
        const int row = wn * 32 + fi * 16 + l15;
        af[fi] = *(const shortx8*)((const char*)Xs + row * 128 + ((slot ^ (row & 7)) << 4));
      }
#pragma unroll
      for (int fj = 0; fj < 2; ++fj) {
        const int col = wm * 32 + fj * 16 + l15;
        bfr[fj] = *(const shortx8*)((const char*)Ws + col * 128 + ((slot ^ (col & 7)) << 4));
      }
#pragma unroll
      for (int fi = 0; fi < 2; ++fi)
#pragma unroll
        for (int fj = 0; fj < 2; ++fj)
          acc[fi][fj] = __builtin_amdgcn_mfma_f32_16x16x32_bf16(af[fi], bfr[fj], acc[fi][fj], 0, 0, 0);
    }
  }
}

// ---------------------------------------------------------------------------
// One launch, three GEMM sets (all K=512, bf16 in):
//   bid [0,256):    EH (T*B,M) f32 = exp(2 * hid . Wh^T)      64n x 4m tiles
//   bid [256,512):  EC (S*B,M) f32 = exp(2 * ctx . Wc^T)      64n x 4m tiles
//   bid [512,1024): CWT ((S,B),H) bf16 = ctx . Wa^T           64n x 8m tiles
// ---------------------------------------------------------------------------
__global__ __launch_bounds__(256) void gemm_multi(
    const ushort* __restrict__ HB, const ushort* __restrict__ WhB, float* __restrict__ EH,
    const ushort* __restrict__ CB, const ushort* __restrict__ WcB, float* __restrict__ EC,
    const ushort* __restrict__ WaB, ushort* __restrict__ CWT) {
  __shared__ ushort Xs[4096];
  __shared__ ushort Ws[4096];
  const int tid = threadIdx.x;
  const int bid = blockIdx.x;

  const ushort *X, *W;
  int n0, m0;
  if (bid < 512) {
    const int lb = bid & 255;
    n0 = (lb >> 2) << 6; m0 = (lb & 3) << 6;
    X = (bid < 256) ? HB : CB;
    W = (bid < 256) ? WhB : WcB;
  } else {
    const int lb = bid - 512;
    n0 = (lb >> 3) << 6;          // (s,b) row tile
    m0 = (lb & 7) << 6;           // h tile
    X = CB;
    W = WaB;
  }

  floatx4 acc[2][2];
#pragma unroll
  for (int i = 0; i < 2; ++i)
#pragma unroll
    for (int j = 0; j < 2; ++j) acc[i][j] = (floatx4){0.f, 0.f, 0.f, 0.f};

  gemm_core_bf16(X, W, n0, m0, 512, 8, Xs, Ws, tid, acc);

  const int lane = tid & 63, wave = tid >> 6;
  const int wn = wave & 1, wm = wave >> 1;
  const int l15 = lane & 15, lhi = lane >> 4;
  if (bid < 512) {
    float* Y = (bid < 256) ? EH : EC;
#pragma unroll
    for (int fi = 0; fi < 2; ++fi)
#pragma unroll
      for (int fj = 0; fj < 2; ++fj)
#pragma unroll
        for (int r = 0; r < 4; ++r) {
          const int row = n0 + wn * 32 + fi * 16 + lhi * 4 + r;
          const int col = m0 + wm * 32 + fj * 16 + l15;
          Y[(size_t)row * M_DIM + col] = __builtin_amdgcn_exp2f(K2LOG2E * acc[fi][fj][r]);
        }
  } else {
#pragma unroll
    for (int fi = 0; fi < 2; ++fi)
#pragma unroll
      for (int fj = 0; fj < 2; ++fj)
#pragma unroll
        for (int r = 0; r < 4; ++r) {
          const int row = n0 + wn * 32 + fi * 16 + lhi * 4 + r;
          const int col = m0 + wm * 32 + fj * 16 + l15;
          CWT[(size_t)row * H_DIM + col] = bf1(acc[fi][fj][r]);
        }
  }
}

// ---------------------------------------------------------------------------
// z (T,B,H) = alpha_b (T,S) . CW_b (S,H), batched over b. K = S = 128.
// X-side: AWS f32 (T,B,S), coalesced (8 lanes x 32B contiguous per row),
// packed to bf16 in-register, conflict-free swizzled LDS store.
// W-side: CWT bf16 ((s,b),H) scatter-load (L2-hot, small volume) + LDS
// transpose into WsT[h][s] (72-elem rows; reads are uniform-spread b128).
// ---------------------------------------------------------------------------
__global__ __launch_bounds__(256) void zgemm_kernel(
    const float* __restrict__ AWS, const ushort* __restrict__ CWT,
    float* __restrict__ z) {
  __shared__ ushort Xs[4096];
  __shared__ ushort WsT[64 * 72];   // [h][s], row stride 72 (144B)
  const int tid = threadIdx.x;
  const int m0 = blockIdx.x << 6;          // h
  const int n0 = blockIdx.y << 6;          // t
  const int b = blockIdx.z;
  const int lane = tid & 63, wave = tid >> 6;
  const int wn = wave & 1, wm = wave >> 1;
  const int l15 = lane & 15, lhi = lane >> 4;
  const int r = tid >> 3, c8 = tid & 7;    // X staging
  const int lr = tid & 63, ls = tid >> 6;  // W staging (scatter)
  const int sw0 = (c8 ^ (r & 7)) << 4;
  char* xr0 = (char*)Xs + r * 128 + sw0;
  char* xr1 = (char*)Xs + (r + 32) * 128 + sw0;

  // Preload both K-halves (K=128 -> 2 iters of 64).
  float4 xa[2][2], xb[2][2];
  uint4 wv[2][2];
#pragma unroll
  for (int it = 0; it < 2; ++it) {
    const float* p0 = AWS + ((size_t)(n0 + r) * B_DIM + b) * S_DIM + it * 64 + c8 * 8;
    const float* p1 = AWS + ((size_t)(n0 + r + 32) * B_DIM + b) * S_DIM + it * 64 + c8 * 8;
    xa[it][0] = ((const float4*)p0)[0]; xa[it][1] = ((const float4*)p0)[1];
    xb[it][0] = ((const float4*)p1)[0]; xb[it][1] = ((const float4*)p1)[1];
    const ushort* q = CWT + ((size_t)(it * 64 + lr) * B_DIM + b) * H_DIM + m0 + ls * 8;
    wv[it][0] = *(const uint4*)q;
    wv[it][1] = *(const uint4*)(q + 32);
  }

  floatx4 acc[2][2];
#pragma unroll
  for (int i = 0; i < 2; ++i)
#pragma unroll
    for (int j = 0; j < 2; ++j) acc[i][j] = (floatx4){0.f, 0.f, 0.f, 0.f};

#pragma unroll
  for (int it = 0; it < 2; ++it) {
    __syncthreads();
    *(uint4*)xr0 = pack2(xa[it][0], xa[it][1]);
    *(uint4*)xr1 = pack2(xb[it][0], xb[it][1]);
#pragma unroll
    for (int q = 0; q < 2; ++q) {
      const int hb = ls * 8 + q * 32;          // h offset within tile
      const ushort* vs = (const ushort*)&wv[it][q];
#pragma unroll
      for (int i = 0; i < 8; ++i) WsT[(hb + i) * 72 + lr] = vs[i];
    }
    __syncthreads();
#pragma unroll
    for (int ks = 0; ks < 2; ++ks) {
      const int slot = lhi + (ks << 2);
      shortx8 af[2], bfr[2];
#pragma unroll
      for (int fi = 0; fi < 2; ++fi) {
        const int row = wn * 32 + fi * 16 + l15;
        af[fi] = *(const shortx8*)((const char*)Xs + row * 128 + ((slot ^ (row & 7)) << 4));
      }
#pragma unroll
      for (int fj = 0; fj < 2; ++fj) {
        const int col = wm * 32 + fj * 16 + l15;
        bfr[fj] = *(const shortx8*)((const char*)WsT + col * 144 + (slot << 4));
      }
#pragma unroll
      for (int fi = 0; fi < 2; ++fi)
#pragma unroll
        for (int fj = 0; fj < 2; ++fj)
          acc[fi][fj] = __builtin_amdgcn_mfma_f32_16x16x32_bf16(af[fi], bfr[fj], acc[fi][fj], 0, 0, 0);
    }
  }

#pragma unroll
  for (int fi = 0; fi < 2; ++fi)
#pragma unroll
    for (int fj = 0; fj < 2; ++fj)
#pragma unroll
      for (int r2 = 0; r2 < 4; ++r2) {
        const int t = n0 + wn * 32 + fi * 16 + lhi * 4 + r2;
        const int h = m0 + wm * 32 + fj * 16 + l15;
        z[((size_t)t * B_DIM + b) * H_DIM + h] = acc[fi][fj][r2];
      }
}

// ---------------------------------------------------------------------------
// Fused scores + softmax, exp-factored:
//   alpha(s) = softmax_s( -2 * sum_m w[m] * rcp(EH[t,b,m]*EC[s,b,m] + 1) )
// Writes AWS in (T,B,S) layout (coalesced; feeds zgemm X-side directly).
// ---------------------------------------------------------------------------
__global__ __launch_bounds__(256) void scores_kernel(
    const float* __restrict__ EH, const float* __restrict__ EC,
    const float* __restrict__ w_ff, const float* __restrict__ ctx_mask,
    float* __restrict__ aws) {
  __shared__ float4 ec[2][8][128];
  __shared__ float4 eh[2][8][8];
  __shared__ float4 wf[2][8];
  __shared__ float msk[S_DIM];
  const int tid = threadIdx.x;
  const int b = blockIdx.y;
  const int t0 = blockIdx.x << 3;
  const int tt = tid >> 6;
  const int st = tid & 63;

  if (tid < S_DIM) msk[tid] = ctx_mask[(size_t)tid * B_DIM + b];

  float4 rec[4], reh, rwf;
#define SLOAD(C)                                                                \
  {                                                                             \
    _Pragma("unroll")                                                           \
    for (int i = 0; i < 4; ++i) {                                               \
      const int idx = tid + (i << 8);                                           \
      const int s_ = idx >> 3, q_ = idx & 7;                                    \
      rec[i] = *(const float4*)(EC + ((size_t)s_ * B_DIM + b) * M_DIM + ((C) << 5) + (q_ << 2)); \
    }                                                                           \
    if (tid < 64)                                                               \
      reh = *(const float4*)(EH + ((size_t)(t0 + (tid >> 3)) * B_DIM + b) * M_DIM + ((C) << 5) + ((tid & 7) << 2)); \
    if (tid < 8) rwf = *(const float4*)(w_ff + ((C) << 5) + (tid << 2));        \
  }
#define SSTORE(BUF)                                                             \
  {                                                                             \
    _Pragma("unroll")                                                           \
    for (int i = 0; i < 4; ++i) {                                               \
      const int idx = tid + (i << 8);                                           \
      ec[BUF][idx & 7][idx >> 3] = rec[i];                                      \
    }                                                                           \
    if (tid < 64) eh[BUF][tid & 7][tid >> 3] = reh;                             \
    if (tid < 8) wf[BUF][tid] = rwf;                                            \
  }

  floatx4 acc[2][2];
#pragma unroll
  for (int i = 0; i < 2; ++i)
#pragma unroll
    for (int j = 0; j < 2; ++j) acc[i][j] = (floatx4){0.f, 0.f, 0.f, 0.f};

  SLOAD(0)
  SSTORE(0)
  __syncthreads();

  for (int c = 0; c < 8; ++c) {
    const int cur = c & 1;
    if (c < 7) SLOAD(c + 1)
#pragma unroll
    for (int q = 0; q < 8; ++q) {
      const float4 w4 = wf[cur][q];
      const float4 e0 = eh[cur][q][2 * tt], e1 = eh[cur][q][2 * tt + 1];
      const float4 c0 = ec[cur][q][st],     c1 = ec[cur][q][st + 64];
#define ACC1(A, E, Cc)                                                 \
  A[0] += w4.x * __builtin_amdgcn_rcpf(E.x * Cc.x + 1.f);              \
  A[1] += w4.y * __builtin_amdgcn_rcpf(E.y * Cc.y + 1.f);              \
  A[2] += w4.z * __builtin_amdgcn_rcpf(E.z * Cc.z + 1.f);              \
  A[3] += w4.w * __builtin_amdgcn_rcpf(E.w * Cc.w + 1.f);
      ACC1(acc[0][0], e0, c0) ACC1(acc[0][1], e0, c1)
      ACC1(acc[1][0], e1, c0) ACC1(acc[1][1], e1, c1)
#undef ACC1
    }
    if (c < 7) {
      SSTORE(cur ^ 1)
      __syncthreads();
    }
  }
#undef SLOAD
#undef SSTORE

  const float mk0 = msk[st], mk1 = msk[st + 64];
  float sc[2][2];
#pragma unroll
  for (int ti = 0; ti < 2; ++ti) {
    const floatx4 a0 = acc[ti][0], a1 = acc[ti][1];
    sc[ti][0] = (mk0 > 0.f) ? -2.f * (a0[0] + a0[1] + a0[2] + a0[3]) : NEG_BIG;
    sc[ti][1] = (mk1 > 0.f) ? -2.f * (a1[0] + a1[1] + a1[2] + a1[3]) : NEG_BIG;
  }
#pragma unroll
  for (int ti = 0; ti < 2; ++ti) {
    float mx = fmaxf(sc[ti][0], sc[ti][1]);
#pragma unroll
    for (int off = 32; off > 0; off >>= 1) mx = fmaxf(mx, __shfl_xor(mx, off));
    const float e0 = __expf(sc[ti][0] - mx), e1 = __expf(sc[ti][1] - mx);
    float sum = e0 + e1;
#pragma unroll
    for (int off = 32; off > 0; off >>= 1) sum += __shfl_xor(sum, off);
    const float rinv = 1.f / sum;
    float* w = aws + ((size_t)(t0 + 2 * tt + ti) * B_DIM + b) * S_DIM;
    w[st] = e0 * rinv;
    w[st + 64] = e1 * rinv;
  }
}

// ---------------------------------------------------------------------------
// AWS (T,B,S) -> out (T,S,B). One block per t.
// ---------------------------------------------------------------------------
__global__ __launch_bounds__(256) void alpha_tr_kernel(
    const float* __restrict__ aws, float* __restrict__ aout) {
  __shared__ float al[32][129];
  const int t = blockIdx.x;
  const int tid = threadIdx.x;
  {
    const int b_ = tid >> 3, q = tid & 7;
    const float* src = aws + ((size_t)t * B_DIM + b_) * S_DIM + q * 16;
#pragma unroll
    for (int i = 0; i < 4; ++i)
      *(float4*)&al[b_][q * 16 + i * 4] = ((const float4*)src)[i];
  }
  __syncthreads();
  {
    const int s = tid >> 1, half = tid & 1;
    float* dst = aout + ((size_t)t * S_DIM + s) * B_DIM + half * 16;
#pragma unroll
    for (int i = 0; i < 4; ++i) {
      float4 o;
      o.x = al[half * 16 + i * 4 + 0][s];
      o.y = al[half * 16 + i * 4 + 1][s];
      o.z = al[half * 16 + i * 4 + 2][s];
      o.w = al[half * 16 + i * 4 + 3][s];
      ((float4*)dst)[i] = o;
    }
  }
}

// ---------------------------------------------------------------------------
extern "C" void kernel_launch(void* const* d_in, const int* in_sizes, int n_in,
                              void* d_out, int out_size, void* d_ws, size_t ws_size,
                              hipStream_t stream) {
  const float* hid       = (const float*)d_in[0];   // (T,B,H)
  const float* ctx       = (const float*)d_in[1];   // (S,B,C)
  const float* ctx_mask  = (const float*)d_in[2];   // (S,B)
  const float* W_hid2mid = (const float*)d_in[3];   // (M,H)
  const float* W_ctx2mid = (const float*)d_in[4];   // (M,C)
  const float* w_ff      = (const float*)d_in[5];   // (M,)
  const float* W_att2hid = (const float*)d_in[6];   // (H,C)
  float* out = (float*)d_out;
  float* ws  = (float*)d_ws;

  const size_t MEG = 1 << 20;
  float*  EH  = ws;                            // 1M f32
  float*  EC  = ws + MEG;                      // 1M f32
  float*  AWS = ws + 2 * MEG;                  // (T,B,S) 0.5M f32
  ushort* CWT = (ushort*)(ws + 2 * MEG + MEG / 2);  // ((S,B),H) 2M bf16
  ushort* HB  = (ushort*)(ws + 4 * MEG);       // hid bf16, 2M
  ushort* CB  = (ushort*)(ws + 5 * MEG);       // ctx bf16, 2M
  ushort* WhB = (ushort*)(ws + 6 * MEG);       // 128K
  ushort* WcB = WhB + 131072;                  // 128K
  ushort* WaB = WcB + 131072;                  // 256K
  float* alpha_out = out;                               // (T,S,B)
  float* z_out     = out + T_DIM * S_DIM * B_DIM;       // (T,B,H)

  dim3 blk(256);
  cvt_kernel<<<2304, blk, 0, stream>>>(hid, HB, 262144, ctx, CB, 262144,
                                       W_hid2mid, WhB, 16384, W_ctx2mid, WcB, 16384,
                                       W_att2hid, WaB, 32768);
  // EH = exp(2*hid.Wh^T), EC = exp(2*ctx.Wc^T), CWT = ctx.Wa^T (bf16)
  gemm_multi<<<1024, blk, 0, stream>>>(HB, WhB, EH, CB, WcB, EC, WaB, CWT);
  // fused tanh-scores + masked softmax -> AWS (T,B,S)
  scores_kernel<<<dim3(T_DIM / 8, B_DIM), blk, 0, stream>>>(EH, EC, w_ff, ctx_mask, AWS);
  // alpha output (T,S,B)
  alpha_tr_kernel<<<T_DIM, blk, 0, stream>>>(AWS, alpha_out);
  // z (T,B,H) = alpha_b . CW_b
  zgemm_kernel<<<dim3(H_DIM / 64, T_DIM / 64, B_DIM), blk, 0, stream>>>(AWS, CWT, z_out);
}